// Round 1
// baseline (919.309 us; speedup 1.0000x reference)
//
#include <hip/hip_runtime.h>

// Equivariant linear layer, fp32.
//   out[n, SEG + o*D + m] = sum_i x[n, i*D+m] * w[o, i*D+m]  (+ bias for 0e)
// Unified view: out[n,o,j%D] += x[n,j] * w[o,j], j = 0..L-1
//   0e: L=128 D=1 O=128   1o: L=192 D=3 O=64   2e: L=160 D=5 O=32
//
// Structure per kernel (template):
//  - lane = output channel within an OH-wide o-slice; block handles NSTREAM
//    node streams of T nodes each.
//  - weights staged once to LDS in natural [o][k] layout, XOR-swizzled
//    (elem ^ ((o&7)<<2)) so per-lane ds_read_b128 along k is conflict-free.
//  - x read as wave-(half-wave-)uniform dwordx4 VMEM loads, VGPR-laundered so
//    they can never become s_loads (which would serialize against LDS reads
//    on lgkmcnt); explicit depth-2 software pipeline (two buffer sets).
//  - O split across HALVES blocks (0e, 1o) to cut LDS and raise occupancy;
//    the re-read of x by the sibling block is L3-resident.

#define OUT_STRIDE 480

template <int L, int D, int OH, int HALVES, int T, int SEG, bool BIAS, int MINW>
__global__ __launch_bounds__(256, MINW) void lin_kernel(
    const float* __restrict__ x, const float* __restrict__ w,
    const float* __restrict__ bias, float* __restrict__ out, int n_nodes) {
  constexpr int NC = L / 4;          // float4 chunks per node row
  constexpr int NSTREAM = 256 / OH;  // node streams per block
  __shared__ __align__(16) float wT[OH * L];

  const int ohalf = (HALVES > 1) ? (int)(blockIdx.x & (HALVES - 1)) : 0;
  const int tile = (HALVES > 1) ? (int)(blockIdx.x >> 1) : (int)blockIdx.x;

  // ---- stage this block's o-slice of weights, swizzled ----
  {
    const float* __restrict__ wseg = w + (size_t)ohalf * OH * L;
    for (int f = threadIdx.x; f < OH * L; f += 256) {
      int o = f / L;  // constant divisor
      wT[f ^ ((o & 7) << 2)] = wseg[f];
    }
  }
  __syncthreads();

  const int o = threadIdx.x & (OH - 1);
  const int stream = threadIdx.x / OH;
  const int n0 = (tile * NSTREAM + stream) * T;
  if (n0 >= n_nodes) return;

  const int wrow = o * L;            // elem index of this lane's weight row
  const int swzm = (o & 7) << 2;     // elem-level XOR swizzle mask

  // Launder 0 through a VGPR: x addressing becomes provably divergent ->
  // global_load_dwordx4 (vmcnt), never s_load.
  int vzero;
  asm volatile("v_mov_b32 %0, 0" : "=v"(vzero));
  const float4* __restrict__ x4 =
      reinterpret_cast<const float4*>(x + (size_t)n0 * L) + vzero;

  const int og = ohalf * OH + o;
  float* __restrict__ ob = out + (size_t)n0 * OUT_STRIDE + SEG + og * D;
  float bv = 0.f;
  if constexpr (BIAS) bv = bias[og];

#define FMA_CHUNK(JC, XBUF)                                                    \
  {                                                                            \
    const float4 wv =                                                          \
        *reinterpret_cast<const float4*>(&wT[(wrow + 4 * (JC)) ^ swzm]);       \
    _Pragma("unroll") for (int t = 0; t < T; ++t) {                            \
      acc[t * D + (4 * (JC) + 0) % D] =                                        \
          fmaf(XBUF[t].x, wv.x, acc[t * D + (4 * (JC) + 0) % D]);              \
      acc[t * D + (4 * (JC) + 1) % D] =                                        \
          fmaf(XBUF[t].y, wv.y, acc[t * D + (4 * (JC) + 1) % D]);              \
      acc[t * D + (4 * (JC) + 2) % D] =                                        \
          fmaf(XBUF[t].z, wv.z, acc[t * D + (4 * (JC) + 2) % D]);              \
      acc[t * D + (4 * (JC) + 3) % D] =                                        \
          fmaf(XBUF[t].w, wv.w, acc[t * D + (4 * (JC) + 3) % D]);              \
    }                                                                          \
  }

  if (n0 + T <= n_nodes) {
    float acc[T * D];
#pragma unroll
    for (int i = 0; i < T * D; ++i) acc[i] = 0.f;

    // depth-2 pipeline: chunks jc (xa) and jc+1 (xb) resident; while
    // consuming jc we issue jc+2, while consuming jc+1 we issue jc+3.
    float4 xa[T], xb[T];
#pragma unroll
    for (int t = 0; t < T; ++t) xa[t] = x4[t * NC + 0];
#pragma unroll
    for (int t = 0; t < T; ++t) xb[t] = x4[t * NC + 1];

#pragma unroll
    for (int jc = 0; jc < NC; jc += 2) {
      FMA_CHUNK(jc, xa);
      if (jc + 2 < NC) {
#pragma unroll
        for (int t = 0; t < T; ++t) xa[t] = x4[t * NC + jc + 2];
      }
      FMA_CHUNK(jc + 1, xb);
      if (jc + 3 < NC) {
#pragma unroll
        for (int t = 0; t < T; ++t) xb[t] = x4[t * NC + jc + 3];
      }
    }

#pragma unroll
    for (int t = 0; t < T; ++t) {
#pragma unroll
      for (int m = 0; m < D; ++m)
        ob[(size_t)t * OUT_STRIDE + m] = acc[t * D + m] + bv;
    }
  } else {
    // tail: per-node; chunk groups of D keep accumulator indices
    // compile-time ((4*(g*D+c)+e)%D == (4c+e)%D).
    const int rem = n_nodes - n0;
    for (int t = 0; t < rem; ++t) {
      float accs[D];
#pragma unroll
      for (int m = 0; m < D; ++m) accs[m] = 0.f;
      for (int g = 0; g < NC / D; ++g) {
#pragma unroll
        for (int c = 0; c < D; ++c) {
          const int jc2 = g * D + c;
          const float4 xv = x4[t * NC + jc2];
          const float4 wv =
              *reinterpret_cast<const float4*>(&wT[(wrow + 4 * jc2) ^ swzm]);
          accs[(4 * c + 0) % D] = fmaf(xv.x, wv.x, accs[(4 * c + 0) % D]);
          accs[(4 * c + 1) % D] = fmaf(xv.y, wv.y, accs[(4 * c + 1) % D]);
          accs[(4 * c + 2) % D] = fmaf(xv.z, wv.z, accs[(4 * c + 2) % D]);
          accs[(4 * c + 3) % D] = fmaf(xv.w, wv.w, accs[(4 * c + 3) % D]);
        }
      }
#pragma unroll
      for (int m = 0; m < D; ++m)
        ob[(size_t)t * OUT_STRIDE + m] = accs[m] + bv;
    }
  }
#undef FMA_CHUNK
}

extern "C" void kernel_launch(void* const* d_in, const int* in_sizes, int n_in,
                              void* d_out, int out_size, void* d_ws,
                              size_t ws_size, hipStream_t stream) {
  const float* x0e = (const float*)d_in[0];
  const float* x1o = (const float*)d_in[1];
  const float* x2e = (const float*)d_in[2];
  const float* w0e = (const float*)d_in[3];
  const float* w1o = (const float*)d_in[4];
  const float* w2e = (const float*)d_in[5];
  const float* bias = (const float*)d_in[6];
  float* out = (float*)d_out;

  const int n = in_sizes[0] / 128;  // N nodes

  // 0e: L=128 D=1, o-slice 64 (2 halves), 4 streams x 8 nodes = 32/tile
  const int tiles0 = (n + 31) / 32;
  lin_kernel<128, 1, 64, 2, 8, 0, true, 4>
      <<<tiles0 * 2, 256, 0, stream>>>(x0e, w0e, bias, out, n);

  // 1o: L=192 D=3, o-slice 32 (2 halves), 8 streams x 8 nodes = 64/tile
  const int tiles1 = (n + 63) / 64;
  lin_kernel<192, 3, 32, 2, 8, 128, false, 4>
      <<<tiles1 * 2, 256, 0, stream>>>(x1o, w1o, nullptr, out, n);

  // 2e: L=160 D=5, all 32 outputs per block, 8 streams x 8 nodes = 64/tile
  const int tiles2 = (n + 63) / 64;
  lin_kernel<160, 5, 32, 1, 8, 320, false, 3>
      <<<tiles2, 256, 0, stream>>>(x2e, w2e, nullptr, out, n);
}